// Round 1
// baseline (180.899 us; speedup 1.0000x reference)
//
#include <hip/hip_runtime.h>
#include <cstddef>
#include <cstdint>

// SAT layout per channel: [1025][1025] f32, sat[y][x] = sum over rows<y, cols<x.
#define SATW 1025
#define SATCH (1025 * 1025)

// ---------------- Kernel A: per-row prefix sum (f64 accumulate, f32 store) ----
// grid = g*1024 blocks (one per local-channel/row), block = 256 threads.
__global__ void rowscan_kernel(const float* __restrict__ in,
                               float* __restrict__ sat, int c0) {
    int b  = blockIdx.x;
    int cl = b >> 10;        // local channel within group
    int y  = b & 1023;
    int c  = c0 + cl;
    const float4* row = (const float4*)(in + ((size_t)(c * 1024 + y)) * 1024);
    int t = threadIdx.x;
    float4 v = row[t];
    double d0 = v.x, d1 = v.y, d2 = v.z, d3 = v.w;
    double L = d0 + d1 + d2 + d3;

    int lane = t & 63, wv = t >> 6;
    double s = L;
#pragma unroll
    for (int off = 1; off < 64; off <<= 1) {
        double n = __shfl_up(s, off, 64);
        if (lane >= off) s += n;
    }
    __shared__ double wsum[4];
    if (lane == 63) wsum[wv] = s;
    __syncthreads();
    double base = s - L;                 // exclusive within wave
    for (int i = 0; i < wv; ++i) base += wsum[i];

    float* orow = sat + ((size_t)cl * SATW + (size_t)(y + 1)) * SATW;
    double p0 = base + d0, p1 = p0 + d1, p2 = p1 + d2, p3 = p2 + d3;
    int x = t * 4 + 1;
    orow[x]     = (float)p0;
    orow[x + 1] = (float)p1;
    orow[x + 2] = (float)p2;
    orow[x + 3] = (float)p3;
    if (t == 0) orow[0] = 0.0f;
}

// ---------------- Kernel B1: per-column chunk sums (128 rows per chunk) -------
// grid = dim3(5, g, 8), block = 256. partial[(cl*8+ch)*SATW + x] (f64)
__global__ void colsum_kernel(const float* __restrict__ sat,
                              double* __restrict__ partial) {
    int x  = blockIdx.x * 256 + threadIdx.x;
    int cl = blockIdx.y;
    int ch = blockIdx.z;
    if (x >= SATW) return;
    const float* base = sat + (size_t)cl * SATCH +
                        ((size_t)(1 + ch * 128)) * SATW + x;
    double s = 0.0;
#pragma unroll 4
    for (int i = 0; i < 128; ++i) s += (double)base[(size_t)i * SATW];
    partial[((size_t)cl * 8 + ch) * SATW + x] = s;
}

// ---------------- Kernel B2: exclusive scan of the 8 chunk sums per column ---
// grid = dim3(5, g), block = 256.
__global__ void scanpartial_kernel(double* __restrict__ partial) {
    int x  = blockIdx.x * 256 + threadIdx.x;
    int cl = blockIdx.y;
    if (x >= SATW) return;
    double* p = partial + (size_t)cl * 8 * SATW + x;
    double run = 0.0;
#pragma unroll
    for (int ch = 0; ch < 8; ++ch) {
        double v = p[(size_t)ch * SATW];
        p[(size_t)ch * SATW] = run;      // exclusive prefix
        run += v;
    }
}

// ---------------- Kernel B3: propagate — inclusive column scan per chunk -----
// grid = dim3(5, g, 8), block = 256.
__global__ void colscan_kernel(float* __restrict__ sat,
                               const double* __restrict__ partial) {
    int x  = blockIdx.x * 256 + threadIdx.x;
    int cl = blockIdx.y;
    int ch = blockIdx.z;
    if (x >= SATW) return;
    float* base = sat + (size_t)cl * SATCH;
    double run = partial[((size_t)cl * 8 + ch) * SATW + x];
    if (ch == 0) base[x] = 0.0f;         // SAT row 0 = zeros
    float* p = base + ((size_t)(1 + ch * 128)) * SATW + x;
#pragma unroll 4
    for (int i = 0; i < 128; ++i) {
        run += (double)p[(size_t)i * SATW];
        p[(size_t)i * SATW] = (float)run;
    }
}

// ---------------- Kernel C: adaptive 7x7 pool per (roi, channel) wave --------
// One wave per (roi, local channel); lanes 0..48 each handle one bin.
__global__ void pool_kernel(const float* __restrict__ sat,
                            const int* __restrict__ rois,
                            float* __restrict__ out, int c0, int gshift) {
    int lane = threadIdx.x & 63;
    int w    = (blockIdx.x * blockDim.x + threadIdx.x) >> 6;
    int roi  = w >> gshift;
    int cl   = w & ((1 << gshift) - 1);

    const int4 rv = ((const int4*)rois)[roi];   // [y0, x0, y1, x1] pixel coords
    int ymin = rv.x >> 5;                       // // FEAT_STRIDE = 32
    int xmin = rv.y >> 5;
    int Ly   = (rv.z >> 5) + 1 - ymin;          // exclusive length
    int Lx   = (rv.w >> 5) + 1 - xmin;

    double acc = 0.0;
    if (lane < 49) {
        int by = lane / 7;
        int bx = lane - by * 7;
        int ylo = ymin + (by * Ly) / 7;
        int yhi = ymin + ((by + 1) * Ly + 6) / 7;
        int xlo = xmin + (bx * Lx) / 7;
        int xhi = xmin + ((bx + 1) * Lx + 6) / 7;
        const float* s = sat + (size_t)cl * SATCH;
        double v = (double)s[(size_t)yhi * SATW + xhi]
                 - (double)s[(size_t)ylo * SATW + xhi]
                 - (double)s[(size_t)yhi * SATW + xlo]
                 + (double)s[(size_t)ylo * SATW + xlo];
        acc = v / (double)((yhi - ylo) * (xhi - xlo));
    }
#pragma unroll
    for (int off = 32; off; off >>= 1) acc += __shfl_down(acc, off, 64);
    if (lane == 0) out[(size_t)roi * 8 + (c0 + cl)] = (float)(acc * (1.0 / 49.0));
}

extern "C" void kernel_launch(void* const* d_in, const int* in_sizes, int n_in,
                              void* d_out, int out_size, void* d_ws, size_t ws_size,
                              hipStream_t stream) {
    const float* conv = (const float*)d_in[0];   // (1, 8, 1024, 1024) f32
    const int*   rois = (const int*)d_in[1];     // (8192, 4) int
    float*       out  = (float*)d_out;           // (8192, 2, 4) f32 flat
    int n_roi = in_sizes[1] / 4;

    // Pick the largest channel-group that fits in workspace:
    //   SAT:     g * 1025*1025 f32  (rounded up to 16B)
    //   partial: g * 8 * 1025 f64
    int gshift = 3;
    while (gshift > 0) {
        size_t g = (size_t)1 << gshift;
        size_t sat_b = ((g * SATCH * 4 + 15) & ~(size_t)15);
        size_t need  = sat_b + g * 8 * SATW * 8;
        if (need <= ws_size) break;
        --gshift;
    }
    int g = 1 << gshift;
    size_t sat_bytes = (((size_t)g * SATCH * 4 + 15) & ~(size_t)15);
    float*  sat     = (float*)d_ws;
    double* partial = (double*)((char*)d_ws + sat_bytes);

    for (int c0 = 0; c0 < 8; c0 += g) {
        rowscan_kernel<<<g * 1024, 256, 0, stream>>>(conv, sat, c0);
        colsum_kernel<<<dim3(5, g, 8), 256, 0, stream>>>(sat, partial);
        scanpartial_kernel<<<dim3(5, g), 256, 0, stream>>>(partial);
        colscan_kernel<<<dim3(5, g, 8), 256, 0, stream>>>(sat, partial);
        pool_kernel<<<(n_roi * g) / 4, 256, 0, stream>>>(sat, rois, out, c0, gshift);
    }
}

// Round 2
// 134.748 us; speedup vs baseline: 1.3425x; 1.3425x over previous
//
#include <hip/hip_runtime.h>
#include <cstddef>
#include <cstdint>

// Channel-interleaved SAT: sat[(y*1025 + x)*8 + c], y,x in [0,1025), c in [0,8).
// sat[y][x][c] = sum over rows<y, cols<x of channel c.
#define SATW 1025
#define W8   8200          // 1025 * 8 floats per y-row
#define NCH  8

// ---------------- Kernel A: row prefix sums, planar in -> interleaved out ----
// One block per y. 4 waves; wave w scans channels 2w and 2w+1 independently
// (chunked wave scan, f64 accumulate), stages to LDS, then a fully-coalesced
// float4 write of the 32.8 KB interleaved row.
__global__ __launch_bounds__(256) void rowscan_kernel(const float* __restrict__ in,
                                                      float* __restrict__ sat) {
    const int y    = blockIdx.x;
    const int t    = threadIdx.x;
    const int lane = t & 63;
    const int wv   = t >> 6;

    __shared__ float lds[NCH][1024];

    for (int k = 0; k < 2; ++k) {
        const int c = wv * 2 + k;
        const float4* r4 = (const float4*)(in + ((size_t)c * 1024 + y) * 1024);
        double chunkbase = 0.0;
#pragma unroll
        for (int j = 0; j < 4; ++j) {           // 4 chunks of 256 floats
            float4 a = r4[lane + 64 * j];       // coalesced per instruction
            double v0 = a.x, v1 = a.y, v2 = a.z, v3 = a.w;
            double s = v0 + v1 + v2 + v3;
            double ps = s;                      // inclusive scan of lane sums
#pragma unroll
            for (int off = 1; off < 64; off <<= 1) {
                double n = __shfl_up(ps, off, 64);
                if (lane >= off) ps += n;
            }
            double base = chunkbase + ps - s;   // exclusive prefix for this lane
            double p0 = base + v0, p1 = p0 + v1, p2 = p1 + v2, p3 = p2 + v3;
            float4 o = make_float4((float)p0, (float)p1, (float)p2, (float)p3);
            ((float4*)lds[c])[lane + 64 * j] = o;   // contiguous -> conflict-free
            chunkbase += __shfl(ps, 63, 64);        // chunk total broadcast
        }
    }
    __syncthreads();

    // Interleaved row write: flat f -> x = f>>3, c = f&7; val = x ? lds[c][x-1] : 0
    float* orow = sat + (size_t)(y + 1) * W8;
    for (int f4 = t; f4 < W8 / 4; f4 += 256) {
        int f = f4 * 4;
        float4 o;
        float* po = (float*)&o;
#pragma unroll
        for (int j = 0; j < 4; ++j) {
            int ff = f + j;
            int x = ff >> 3, c = ff & 7;
            po[j] = x ? lds[c][x - 1] : 0.0f;   // 2-way LDS alias: free
        }
        ((float4*)orow)[f4] = o;                // coalesced global store
    }
}

// ---------------- Kernel B1: per-column chunk sums (R rows per chunk) --------
// grid = dim3(33, C). Column = flat (x,c) index f; stride between rows = W8.
__global__ void colsum_kernel(const float* __restrict__ sat,
                              double* __restrict__ partial, int R) {
    int f  = blockIdx.x * 256 + threadIdx.x;
    int ch = blockIdx.y;
    if (f >= W8) return;
    const float* p = sat + ((size_t)(1 + ch * R)) * W8 + f;
    double s = 0.0;
#pragma unroll 4
    for (int i = 0; i < R; ++i) s += (double)p[(size_t)i * W8];
    partial[(size_t)ch * W8 + f] = s;
}

// ---------------- Kernel B2: exclusive scan of the C chunk sums per column ---
__global__ void scanpartial_kernel(double* __restrict__ partial, int C) {
    int f = blockIdx.x * 256 + threadIdx.x;
    if (f >= W8) return;
    double run = 0.0;
    for (int ch = 0; ch < C; ++ch) {
        double v = partial[(size_t)ch * W8 + f];
        partial[(size_t)ch * W8 + f] = run;
        run += v;
    }
}

// ---------------- Kernel B3: propagate — inclusive column scan per chunk -----
__global__ void colscan_kernel(float* __restrict__ sat,
                               const double* __restrict__ partial, int R) {
    int f  = blockIdx.x * 256 + threadIdx.x;
    int ch = blockIdx.y;
    if (f >= W8) return;
    double run = partial[(size_t)ch * W8 + f];
    if (ch == 0) sat[f] = 0.0f;             // SAT row y=0 is zeros
    float* p = sat + ((size_t)(1 + ch * R)) * W8 + f;
#pragma unroll 4
    for (int i = 0; i < R; ++i) {
        run += (double)p[(size_t)i * W8];
        p[(size_t)i * W8] = (float)run;
    }
}

// ---------------- Kernel C: one wave per ROI, all 8 channels -----------------
// Lane<49 owns one 7x7 bin: 4 corners x 8 interleaved channels (2 float4 each).
__global__ __launch_bounds__(256) void pool_kernel(const float* __restrict__ sat,
                                                   const int* __restrict__ rois,
                                                   float* __restrict__ out,
                                                   int n_roi) {
    int lane = threadIdx.x & 63;
    int roi  = (blockIdx.x * blockDim.x + threadIdx.x) >> 6;
    if (roi >= n_roi) return;

    const int4 rv = ((const int4*)rois)[roi];   // [y0, x0, y1, x1] pixel coords
    int ymin = rv.x >> 5;                       // / FEAT_STRIDE(32)
    int xmin = rv.y >> 5;
    int Ly   = (rv.z >> 5) + 1 - ymin;
    int Lx   = (rv.w >> 5) + 1 - xmin;

    double acc[NCH];
#pragma unroll
    for (int c = 0; c < NCH; ++c) acc[c] = 0.0;

    if (lane < 49) {
        int by = lane / 7;
        int bx = lane - by * 7;
        int ylo = ymin + (by * Ly) / 7;
        int yhi = ymin + ((by + 1) * Ly + 6) / 7;
        int xlo = xmin + (bx * Lx) / 7;
        int xhi = xmin + ((bx + 1) * Lx + 6) / 7;
        double inv = 1.0 / (double)((yhi - ylo) * (xhi - xlo));

        const float4* hh = (const float4*)(sat + ((size_t)yhi * SATW + xhi) * NCH);
        const float4* lh = (const float4*)(sat + ((size_t)ylo * SATW + xhi) * NCH);
        const float4* hl = (const float4*)(sat + ((size_t)yhi * SATW + xlo) * NCH);
        const float4* ll = (const float4*)(sat + ((size_t)ylo * SATW + xlo) * NCH);
        float4 a0 = hh[0], a1 = hh[1];
        float4 b0 = lh[0], b1 = lh[1];
        float4 c0 = hl[0], c1 = hl[1];
        float4 d0 = ll[0], d1 = ll[1];
        const float* pa = (const float*)&a0;  // a0,a1 adjacent in regs
        const float* pb = (const float*)&b0;
        const float* pc = (const float*)&c0;
        const float* pd = (const float*)&d0;
        float4 tmpa[2] = {a0, a1}, tmpb[2] = {b0, b1}, tmpc[2] = {c0, c1}, tmpd[2] = {d0, d1};
        const float* fa = (const float*)tmpa;
        const float* fb = (const float*)tmpb;
        const float* fc = (const float*)tmpc;
        const float* fd = (const float*)tmpd;
        (void)pa; (void)pb; (void)pc; (void)pd;
#pragma unroll
        for (int c = 0; c < NCH; ++c) {
            double v = (double)fa[c] - (double)fb[c] - (double)fc[c] + (double)fd[c];
            acc[c] = v * inv;
        }
    }

#pragma unroll
    for (int off = 32; off; off >>= 1) {
#pragma unroll
        for (int c = 0; c < NCH; ++c) acc[c] += __shfl_down(acc[c], off, 64);
    }

    if (lane == 0) {
        float4 o0 = make_float4((float)(acc[0] * (1.0 / 49.0)),
                                (float)(acc[1] * (1.0 / 49.0)),
                                (float)(acc[2] * (1.0 / 49.0)),
                                (float)(acc[3] * (1.0 / 49.0)));
        float4 o1 = make_float4((float)(acc[4] * (1.0 / 49.0)),
                                (float)(acc[5] * (1.0 / 49.0)),
                                (float)(acc[6] * (1.0 / 49.0)),
                                (float)(acc[7] * (1.0 / 49.0)));
        float4* po = (float4*)(out + (size_t)roi * NCH);
        po[0] = o0;
        po[1] = o1;
    }
}

extern "C" void kernel_launch(void* const* d_in, const int* in_sizes, int n_in,
                              void* d_out, int out_size, void* d_ws, size_t ws_size,
                              hipStream_t stream) {
    const float* conv = (const float*)d_in[0];   // (1, 8, 1024, 1024) f32
    const int*   rois = (const int*)d_in[1];     // (8192, 4) int32
    float*       out  = (float*)d_out;           // (8192, 2, 4) f32 flat
    int n_roi = in_sizes[1] / 4;

    // Workspace: SAT (interleaved) + f64 partials. Pick largest C that fits.
    const size_t sat_bytes = (size_t)SATW * W8 * 4;   // 33,620,000 (16B-aligned)
    int C = 64;
    while (C > 8 && sat_bytes + (size_t)C * W8 * 8 > ws_size) C >>= 1;
    int R = 1024 / C;

    float*  sat     = (float*)d_ws;
    double* partial = (double*)((char*)d_ws + sat_bytes);

    rowscan_kernel<<<1024, 256, 0, stream>>>(conv, sat);
    colsum_kernel<<<dim3(33, C), 256, 0, stream>>>(sat, partial, R);
    scanpartial_kernel<<<33, 256, 0, stream>>>(partial, C);
    colscan_kernel<<<dim3(33, C), 256, 0, stream>>>(sat, partial, R);
    pool_kernel<<<(n_roi + 3) / 4, 256, 0, stream>>>(sat, rois, out, n_roi);
}